// Round 2
// baseline (82.724 us; speedup 1.0000x reference)
//
#include <hip/hip_runtime.h>

#define NN 16
#define CC 16
#define HH 52
#define WW 52
#define KKN 9           // 3x3 kernel positions
#define OO 16
#define NBLK (NN * CC)  // 256 blocks, one per (n,c) image
#define INV_L2 (1.0f / 22500.0f)   // 1/(KK*L) = 1/(9*2500)

// Single fused kernel.
// Phase 1 (all 256 blocks, one per (n,c)): windowed sums
//   T[nc,kk] = sum over shifted 50x50 window of x
//   Q[nc,kk] = sum of squares over same window
// computed via full-row/column sums minus edge corrections (O(H*W), not O(9*L)).
// Phase 2 (last block to finish, via device-scope atomic counter):
//   out[n,o]  = sum_c ( sum_kk W^2*Q - (sum_kk W*T)^2/22500 ) / (sum_kk W)
//   final[i,n,o] = out[n,o] + B[i,n]   (broadcast over leading O)
__global__ __launch_bounds__(64) void tvar_fused(const float* __restrict__ x,
                                                 const float* __restrict__ Wt,
                                                 const float* __restrict__ B,
                                                 float* __restrict__ T,
                                                 float* __restrict__ Q,
                                                 int* __restrict__ counter,
                                                 float* __restrict__ out) {
    __shared__ float img[HH * WW];          // 10816 B
    __shared__ float R[6][HH];              // row sums: 3 col-windows x {sum, sum^2}
    __shared__ float colfull[6], e0[6], e1[6], e50[6], e51[6];
    __shared__ int   is_last;
    __shared__ float sW[OO * CC * KKN];     // phase-2 staging (9216 B each)
    __shared__ float sT[NN * CC * KKN];
    __shared__ float sQ[NN * CC * KKN];
    __shared__ float sB[OO * CC];

    const int nc = blockIdx.x;
    const int t  = threadIdx.x;

    // ---- Phase 1: coalesced float4 stage of the 52x52 image ----
    const float4* src = (const float4*)(x + nc * (HH * WW));
    float4* dst = (float4*)img;
    #pragma unroll
    for (int i = 0; i < 11; ++i) {
        const int idx = t + i * 64;
        if (idx < (HH * WW) / 4) dst[idx] = src[idx];
    }
    __syncthreads();

    // Per-row full sums + edge corrections -> 3 windowed row sums (cols j..j+49)
    if (t < HH) {
        const float* row = img + t * WW;
        float s = 0.f, s2 = 0.f;
        #pragma unroll
        for (int xc = 0; xc < WW; ++xc) { const float v = row[xc]; s += v; s2 += v * v; }
        const float a0 = row[0], a1 = row[1], a50 = row[50], a51 = row[51];
        R[0][t] = s  - a50 - a51;            // cols 0..49
        R[1][t] = s  - a0  - a51;            // cols 1..50
        R[2][t] = s  - a0  - a1;             // cols 2..51
        R[3][t] = s2 - a50 * a50 - a51 * a51;
        R[4][t] = s2 - a0  * a0  - a51 * a51;
        R[5][t] = s2 - a0  * a0  - a1  * a1;
    }
    __syncthreads();

    // Column reduce over all 52 rows; keep edge rows for the row-window correction
    if (t < 6) {
        float s = 0.f;
        for (int r = 0; r < HH; ++r) s += R[t][r];
        colfull[t] = s;
        e0[t] = R[t][0]; e1[t] = R[t][1]; e50[t] = R[t][50]; e51[t] = R[t][51];
    }
    __syncthreads();

    // T[(i,j)] = rows i..i+49 of R[j]; Q likewise with R[3+j]
    if (t < KKN) {
        const int i = t / 3, j = t % 3;
        const float c1 = (i == 0) ? (e50[j] + e51[j])
                       : (i == 1) ? (e0[j]  + e51[j])
                                  : (e0[j]  + e1[j]);
        T[nc * KKN + t] = colfull[j] - c1;
        const float c2 = (i == 0) ? (e50[3 + j] + e51[3 + j])
                       : (i == 1) ? (e0[3 + j]  + e51[3 + j])
                                  : (e0[3 + j]  + e1[3 + j]);
        Q[nc * KKN + t] = colfull[3 + j] - c2;
    }

    // ---- Device-scope release + last-block election ----
    __threadfence();                         // each thread releases its own T/Q writes
    __syncthreads();                         // all writes + fences in this block done
    if (t == 0) {
        const int old = __hip_atomic_fetch_add(counter, 1, __ATOMIC_ACQ_REL,
                                               __HIP_MEMORY_SCOPE_AGENT);
        is_last = (old == NBLK - 1) ? 1 : 0;
    }
    __syncthreads();
    if (!is_last) return;

    // ---- Phase 2 (last block only, 64 threads) ----
    {
        const float4* gw = (const float4*)Wt;
        const float4* gt = (const float4*)T;
        const float4* gq = (const float4*)Q;
        for (int i = t; i < (OO * CC * KKN) / 4; i += 64) {
            ((float4*)sW)[i] = gw[i];
            ((float4*)sT)[i] = gt[i];
            ((float4*)sQ)[i] = gq[i];
        }
        const float4* gb = (const float4*)B;
        if (t < (OO * CC) / 4) ((float4*)sB)[t] = gb[t];
    }
    __syncthreads();

    float accv[4];
    #pragma unroll
    for (int p = 0; p < 4; ++p) {
        const int pair = t + p * 64;         // pair = n*16 + o
        const int n = pair >> 4;
        const int o = pair & 15;
        float acc = 0.f;
        #pragma unroll
        for (int c = 0; c < CC; ++c) {
            const float* w  = sW + (o * CC + c) * KKN;
            const float* tt = sT + (n * CC + c) * KKN;
            const float* qq = sQ + (n * CC + c) * KKN;
            float size = 0.f, s1 = 0.f, sq = 0.f;
            #pragma unroll
            for (int k = 0; k < KKN; ++k) {
                const float wv = w[k];
                size += wv;
                s1   += wv * tt[k];
                sq   += wv * wv * qq[k];
            }
            acc += (sq - s1 * s1 * INV_L2) / size;
        }
        accv[p] = acc;
    }

    // final[i, n, o] = acc(n,o) + B[i, n]; coalesced stores across t
    #pragma unroll
    for (int i = 0; i < OO; ++i) {
        #pragma unroll
        for (int p = 0; p < 4; ++p) {
            const int pair = t + p * 64;
            out[i * 256 + pair] = accv[p] + sB[i * CC + (pair >> 4)];
        }
    }
}

extern "C" void kernel_launch(void* const* d_in, const int* in_sizes, int n_in,
                              void* d_out, int out_size, void* d_ws, size_t ws_size,
                              hipStream_t stream) {
    const float* x  = (const float*)d_in[0];
    const float* Wt = (const float*)d_in[1];
    const float* B  = (const float*)d_in[2];
    float* out = (float*)d_out;

    int*   counter = (int*)d_ws;                     // first 64 B reserved
    float* T = (float*)d_ws + 16;                    // 64-B aligned
    float* Q = T + NN * CC * KKN;

    hipMemsetAsync(d_ws, 0, 64, stream);             // zero the arrival counter
    tvar_fused<<<NBLK, 64, 0, stream>>>(x, Wt, B, T, Q, counter, out);
}

// Round 3
// 79.850 us; speedup vs baseline: 1.0360x; 1.0360x over previous
//
#include <hip/hip_runtime.h>

#define NN 16
#define CC 16
#define HH 52
#define WW 52
#define KKN 9           // 3x3 kernel positions
#define OO 16
#define NBLK (NN * CC)  // 256 blocks, one per (n,c) image
#define INV_L2 (1.0f / 22500.0f)   // 1/(KK*L) = 1/(9*2500)
#define MAGIC 0x13579BDF            // sentinel != 0xAAAAAAAA poison

// Single fused kernel, no workspace init required.
// Phase 1 (each of 256 blocks, one per (n,c)): windowed sums over shifted
//   50x50 windows: T[nc,kk] = sum(x), Q[nc,kk] = sum(x^2), kk=(kh,kw),
//   via full column sums minus edge rows, then full col-sum reduce minus
//   edge cols (O(H*W), conflict-free LDS column access).
// Completion: each block release-stores MAGIC into flags[nc] (poison-immune,
//   no memset needed). Block 0 acquire-polls all 256 flags, then:
// Phase 2: out[n,o] = sum_c ( sum_kk W^2*Q - (sum_kk W*T)^2/22500 ) / (sum_kk W)
//   final[i,n,o] = out[n,o] + B[i,n]
__global__ __launch_bounds__(64) void tvar_fused(const float* __restrict__ x,
                                                 const float* __restrict__ Wt,
                                                 const float* __restrict__ B,
                                                 float* __restrict__ T,
                                                 float* __restrict__ Q,
                                                 int* __restrict__ flags,
                                                 float* __restrict__ out) {
    __shared__ float img[HH * WW];          // 10816 B
    __shared__ float Cw[6][HH];             // per-column sums: 3 row-windows x {s, s2}
    __shared__ float colfull[6], e0[6], e1[6], e50[6], e51[6];
    __shared__ float sW[OO * CC * KKN];     // phase-2 staging
    __shared__ float sT[NN * CC * KKN];
    __shared__ float sQ[NN * CC * KKN];
    __shared__ float sB[OO * CC];

    const int nc = blockIdx.x;
    const int t  = threadIdx.x;

    // ---- Phase 1: coalesced float4 stage of the 52x52 image ----
    const float4* src = (const float4*)(x + nc * (HH * WW));
    float4* dst = (float4*)img;
    #pragma unroll
    for (int i = 0; i < 11; ++i) {
        const int idx = t + i * 64;
        if (idx < (HH * WW) / 4) dst[idx] = src[idx];
    }
    __syncthreads();

    // Per-column full sums (lane t -> column t: consecutive banks, no conflict)
    // Row-window i: i=0 -> rows 0..49 (drop 50,51); i=1 -> 1..50; i=2 -> 2..51.
    if (t < WW) {
        float s = 0.f, s2 = 0.f;
        #pragma unroll
        for (int r = 0; r < HH; ++r) { const float v = img[r * WW + t]; s += v; s2 += v * v; }
        const float r0  = img[0 * WW + t],  r1  = img[1 * WW + t];
        const float r50 = img[50 * WW + t], r51 = img[51 * WW + t];
        Cw[0][t] = s  - r50 - r51;
        Cw[1][t] = s  - r0  - r51;
        Cw[2][t] = s  - r0  - r1;
        Cw[3][t] = s2 - r50 * r50 - r51 * r51;
        Cw[4][t] = s2 - r0  * r0  - r51 * r51;
        Cw[5][t] = s2 - r0  * r0  - r1  * r1;
    }
    __syncthreads();

    // Reduce each of the 6 arrays over all 52 columns; keep edge cols
    if (t < 6) {
        float s = 0.f;
        for (int c = 0; c < WW; ++c) s += Cw[t][c];
        colfull[t] = s;
        e0[t] = Cw[t][0]; e1[t] = Cw[t][1]; e50[t] = Cw[t][50]; e51[t] = Cw[t][51];
    }
    __syncthreads();

    // T[kk = i*3+j] = cols j..j+49 of row-window i
    if (t < KKN) {
        const int i = t / 3, j = t % 3;
        const float c1 = (j == 0) ? (e50[i] + e51[i])
                       : (j == 1) ? (e0[i]  + e51[i])
                                  : (e0[i]  + e1[i]);
        T[nc * KKN + t] = colfull[i] - c1;
        const float c2 = (j == 0) ? (e50[3 + i] + e51[3 + i])
                       : (j == 1) ? (e0[3 + i]  + e51[3 + i])
                                  : (e0[3 + i]  + e1[3 + i]);
        Q[nc * KKN + t] = colfull[3 + i] - c2;
    }

    // ---- Publish: device-scope release of this block's T/Q via sentinel flag ----
    __threadfence();                         // release T/Q writes to agent scope
    __syncthreads();
    if (t == 0) {
        __hip_atomic_store(&flags[nc], MAGIC, __ATOMIC_RELEASE,
                           __HIP_MEMORY_SCOPE_AGENT);
    }
    if (nc != 0) return;

    // ---- Block 0: wait for all 256 flags (poison-immune: poison != MAGIC) ----
    #pragma unroll
    for (int p = 0; p < 4; ++p) {
        const int j = t + p * 64;
        while (__hip_atomic_load(&flags[j], __ATOMIC_ACQUIRE,
                                 __HIP_MEMORY_SCOPE_AGENT) != MAGIC) { }
    }
    __syncthreads();

    // ---- Phase 2 (block 0 only, 64 threads) ----
    {
        const float4* gw = (const float4*)Wt;
        const float4* gt = (const float4*)T;
        const float4* gq = (const float4*)Q;
        for (int i = t; i < (OO * CC * KKN) / 4; i += 64) {
            ((float4*)sW)[i] = gw[i];
            ((float4*)sT)[i] = gt[i];
            ((float4*)sQ)[i] = gq[i];
        }
        const float4* gb = (const float4*)B;
        if (t < (OO * CC) / 4) ((float4*)sB)[t] = gb[t];
    }
    __syncthreads();

    float accv[4];
    #pragma unroll
    for (int p = 0; p < 4; ++p) {
        const int pair = t + p * 64;         // pair = n*16 + o
        const int n = pair >> 4;
        const int o = pair & 15;
        float acc = 0.f;
        #pragma unroll
        for (int c = 0; c < CC; ++c) {
            const float* w  = sW + (o * CC + c) * KKN;
            const float* tt = sT + (n * CC + c) * KKN;
            const float* qq = sQ + (n * CC + c) * KKN;
            float size = 0.f, s1 = 0.f, sq = 0.f;
            #pragma unroll
            for (int k = 0; k < KKN; ++k) {
                const float wv = w[k];
                size += wv;
                s1   += wv * tt[k];
                sq   += wv * wv * qq[k];
            }
            acc += (sq - s1 * s1 * INV_L2) / size;
        }
        accv[p] = acc;
    }

    // final[i, n, o] = acc(n,o) + B[i, n]; coalesced stores across t
    #pragma unroll
    for (int i = 0; i < OO; ++i) {
        #pragma unroll
        for (int p = 0; p < 4; ++p) {
            const int pair = t + p * 64;
            out[i * 256 + pair] = accv[p] + sB[i * CC + (pair >> 4)];
        }
    }
}

extern "C" void kernel_launch(void* const* d_in, const int* in_sizes, int n_in,
                              void* d_out, int out_size, void* d_ws, size_t ws_size,
                              hipStream_t stream) {
    const float* x  = (const float*)d_in[0];
    const float* Wt = (const float*)d_in[1];
    const float* B  = (const float*)d_in[2];
    float* out = (float*)d_out;

    int*   flags = (int*)d_ws;                       // 256 ints (poison-immune sentinel)
    float* T = (float*)d_ws + 256;                   // 1 KB offset, aligned
    float* Q = T + NN * CC * KKN;

    tvar_fused<<<NBLK, 64, 0, stream>>>(x, Wt, B, T, Q, flags, out);
}

// Round 4
// 66.289 us; speedup vs baseline: 1.2479x; 1.2046x over previous
//
#include <hip/hip_runtime.h>

#define NN 16
#define CC 16
#define HH 52
#define WW 52
#define KKN 9           // 3x3 kernel positions
#define OO 16
#define INV_L2 (1.0f / 22500.0f)   // 1/(KK*L) = 1/(9*2500)

// Stage 1: per (n,c) image, windowed sums over the 9 shifted 50x50 windows:
//   T[nc,kk] = sum(x), Q[nc,kk] = sum(x^2), kk = kh*3+kw.
// Computed via full per-column sums minus edge ROWS (3 row-windows), then a
// column reduce minus edge COLS (3 col-windows) -> O(H*W) work, and lane t
// reads column t of the LDS image: consecutive banks, conflict-free.
__global__ __launch_bounds__(64) void tvar_stage1(const float* __restrict__ x,
                                                  float* __restrict__ T,
                                                  float* __restrict__ Q) {
    __shared__ float img[HH * WW];          // 10816 B
    __shared__ float Cw[6][HH];             // col sums: 3 row-windows x {s, s2}
    __shared__ float colfull[6], e0[6], e1[6], e50[6], e51[6];

    const int nc = blockIdx.x;
    const int t  = threadIdx.x;

    // Coalesced float4 stage of the 52x52 image (676 float4)
    const float4* src = (const float4*)(x + nc * (HH * WW));
    float4* dst = (float4*)img;
    #pragma unroll
    for (int i = 0; i < 11; ++i) {
        const int idx = t + i * 64;
        if (idx < (HH * WW) / 4) dst[idx] = src[idx];
    }
    __syncthreads();

    // Per-column full sums; row-window i=0: rows 0..49, i=1: 1..50, i=2: 2..51
    if (t < WW) {
        float s = 0.f, s2 = 0.f;
        #pragma unroll
        for (int r = 0; r < HH; ++r) { const float v = img[r * WW + t]; s += v; s2 += v * v; }
        const float r0  = img[0 * WW + t],  r1  = img[1 * WW + t];
        const float r50 = img[50 * WW + t], r51 = img[51 * WW + t];
        Cw[0][t] = s  - r50 - r51;
        Cw[1][t] = s  - r0  - r51;
        Cw[2][t] = s  - r0  - r1;
        Cw[3][t] = s2 - r50 * r50 - r51 * r51;
        Cw[4][t] = s2 - r0  * r0  - r51 * r51;
        Cw[5][t] = s2 - r0  * r0  - r1  * r1;
    }
    __syncthreads();

    // Reduce the 6 arrays over all 52 columns; keep edge columns
    if (t < 6) {
        float s = 0.f;
        for (int c = 0; c < WW; ++c) s += Cw[t][c];
        colfull[t] = s;
        e0[t] = Cw[t][0]; e1[t] = Cw[t][1]; e50[t] = Cw[t][50]; e51[t] = Cw[t][51];
    }
    __syncthreads();

    // T[kk = i*3+j]: col-window j=0 -> cols 0..49 (drop 50,51), j=1 -> 1..50, j=2 -> 2..51
    if (t < KKN) {
        const int i = t / 3, j = t % 3;
        const float c1 = (j == 0) ? (e50[i] + e51[i])
                       : (j == 1) ? (e0[i]  + e51[i])
                                  : (e0[i]  + e1[i]);
        T[nc * KKN + t] = colfull[i] - c1;
        const float c2 = (j == 0) ? (e50[3 + i] + e51[3 + i])
                       : (j == 1) ? (e0[3 + i]  + e51[3 + i])
                                  : (e0[3 + i]  + e1[3 + i]);
        Q[nc * KKN + t] = colfull[3 + i] - c2;
    }
}

// Stage 2: out[n,o] = sum_c ( sum_kk W^2*Q - (sum_kk W*T)^2/22500 ) / (sum_kk W)
// final[i, n, o] = out[n, o] + B[i, n]   (broadcast over leading O)
__global__ __launch_bounds__(256) void tvar_stage2(const float* __restrict__ Wt,
                                                   const float* __restrict__ B,
                                                   const float* __restrict__ T,
                                                   const float* __restrict__ Q,
                                                   float* __restrict__ out) {
    __shared__ float sW[OO * CC * KKN];     // 2304 floats each
    __shared__ float sT[NN * CC * KKN];
    __shared__ float sQ[NN * CC * KKN];
    __shared__ float sB[OO * CC];

    const int t = threadIdx.x;              // t = n*16 + o
    {
        const float4* gw = (const float4*)Wt;
        const float4* gt = (const float4*)T;
        const float4* gq = (const float4*)Q;
        for (int i = t; i < (OO * CC * KKN) / 4; i += 256) {
            ((float4*)sW)[i] = gw[i];
            ((float4*)sT)[i] = gt[i];
            ((float4*)sQ)[i] = gq[i];
        }
        if (t < (OO * CC) / 4) ((float4*)sB)[t] = ((const float4*)B)[t];
    }
    __syncthreads();

    const int n = t >> 4;
    const int o = t & 15;

    float acc = 0.f;
    #pragma unroll
    for (int c = 0; c < CC; ++c) {
        const float* w  = sW + (o * CC + c) * KKN;
        const float* tt = sT + (n * CC + c) * KKN;
        const float* qq = sQ + (n * CC + c) * KKN;
        float size = 0.f, s1 = 0.f, sq = 0.f;
        #pragma unroll
        for (int k = 0; k < KKN; ++k) {
            const float wv = w[k];
            size += wv;
            s1   += wv * tt[k];
            sq   += wv * wv * qq[k];
        }
        acc += (sq - s1 * s1 * INV_L2) / size;
    }

    // final[i, n, o] = acc + B[i, n]; coalesced stores across t
    #pragma unroll
    for (int i = 0; i < OO; ++i) {
        out[i * 256 + t] = acc + sB[i * CC + n];
    }
}

extern "C" void kernel_launch(void* const* d_in, const int* in_sizes, int n_in,
                              void* d_out, int out_size, void* d_ws, size_t ws_size,
                              hipStream_t stream) {
    const float* x  = (const float*)d_in[0];
    const float* Wt = (const float*)d_in[1];
    const float* B  = (const float*)d_in[2];
    float* out = (float*)d_out;

    float* T = (float*)d_ws;                         // 2304 floats
    float* Q = T + NN * CC * KKN;                    // 2304 floats

    tvar_stage1<<<NN * CC, 64, 0, stream>>>(x, T, Q);
    tvar_stage2<<<1, 256, 0, stream>>>(Wt, B, T, Q, out);
}

// Round 5
// 61.298 us; speedup vs baseline: 1.3495x; 1.0814x over previous
//
#include <hip/hip_runtime.h>

#define NN 16
#define CC 16
#define HH 52
#define WW 52
#define KKN 9           // 3x3 kernel positions
#define OO 16
#define INV_L2 (1.0f / 22500.0f)   // 1/(KK*L) = 1/(9*2500)

// Single kernel, 16 blocks (one per n) x 1024 threads (16 waves, one per c).
// No inter-block communication, no workspace.
//
// Phase 1 (wave w = channel c): lane l (<52) reads column l of image (n,c)
// straight from global (coalesced 208B rows), accumulating full column sum s
// and sum-of-squares s2 plus row-edge values (rows 0,1,50,51). The 3 row-
// windows give 6 per-column quantities; column-window totals come from a
// wave butterfly reduce plus column-edge values captured via __shfl from
// lanes 0,1,50,51. Lanes 0..8 write T[c][kk], Q[c][kk] to LDS.
//
// Phase 2 (after one barrier): thread t<256 computes
//   partial(c,o) = (sum_kk W^2 Q - (sum_kk W T)^2/22500) / (sum_kk W)
// reduce over c, then out[i,n,o] = acc(n,o) + B[i,n] broadcast over i.

// wave reduce of v (lanes>=52 must hold 0) -> full sum + column edges 0,1,50,51
#define REDUCE6(v, FULL, E0, E1, E50, E51)                                   \
    {                                                                        \
        E0 = __shfl((v), 0); E1 = __shfl((v), 1);                            \
        E50 = __shfl((v), 50); E51 = __shfl((v), 51);                        \
        float _s = (v);                                                      \
        _s += __shfl_xor(_s, 32); _s += __shfl_xor(_s, 16);                  \
        _s += __shfl_xor(_s, 8);  _s += __shfl_xor(_s, 4);                   \
        _s += __shfl_xor(_s, 2);  _s += __shfl_xor(_s, 1);                   \
        FULL = _s;                                                           \
    }

__global__ __launch_bounds__(1024) void tvar_onepass(const float* __restrict__ x,
                                                     const float* __restrict__ Wt,
                                                     const float* __restrict__ B,
                                                     float* __restrict__ out) {
    __shared__ float sW[OO * CC * KKN];   // 9216 B
    __shared__ float sB[OO * CC];         // 1 KB
    __shared__ float sT[CC][KKN];
    __shared__ float sQ[CC][KKN];
    __shared__ float partial[CC * OO];
    __shared__ float accO[OO];

    const int n = blockIdx.x;
    const int t = threadIdx.x;
    const int w = t >> 6;                 // wave id == channel c
    const int l = t & 63;

    // Stage W (576 float4) and B (64 float4); visibility covered by the
    // phase-1/phase-2 barrier below.
    if (t < (OO * CC * KKN) / 4) ((float4*)sW)[t] = ((const float4*)Wt)[t];
    if (t < (OO * CC) / 4)       ((float4*)sB)[t] = ((const float4*)B)[t];

    // ---- Phase 1: per-wave column sums of image (n, c=w) ----
    float v0 = 0.f, v1 = 0.f, v2 = 0.f, v3 = 0.f, v4 = 0.f, v5 = 0.f;
    if (l < WW) {
        const float* base = x + (n * CC + w) * (HH * WW) + l;
        float s = 0.f, s2 = 0.f;
        float a0 = 0.f, a1 = 0.f, a50 = 0.f, a51 = 0.f;
        #pragma unroll
        for (int r = 0; r < HH; ++r) {
            const float v = base[r * WW];
            s += v; s2 += v * v;
            if (r == 0)  a0  = v;
            if (r == 1)  a1  = v;
            if (r == 50) a50 = v;
            if (r == 51) a51 = v;
        }
        v0 = s  - a50 - a51;              // rows 0..49
        v1 = s  - a0  - a51;              // rows 1..50
        v2 = s  - a0  - a1;               // rows 2..51
        v3 = s2 - a50 * a50 - a51 * a51;
        v4 = s2 - a0  * a0  - a51 * a51;
        v5 = s2 - a0  * a0  - a1  * a1;
    }

    // Wave reduce all 6 arrays (named scalars only — no runtime-indexed regs)
    float F0, F1, F2, F3, F4, F5;
    float P0_0, P1_0, P50_0, P51_0, P0_1, P1_1, P50_1, P51_1;
    float P0_2, P1_2, P50_2, P51_2, P0_3, P1_3, P50_3, P51_3;
    float P0_4, P1_4, P50_4, P51_4, P0_5, P1_5, P50_5, P51_5;
    REDUCE6(v0, F0, P0_0, P1_0, P50_0, P51_0);
    REDUCE6(v1, F1, P0_1, P1_1, P50_1, P51_1);
    REDUCE6(v2, F2, P0_2, P1_2, P50_2, P51_2);
    REDUCE6(v3, F3, P0_3, P1_3, P50_3, P51_3);
    REDUCE6(v4, F4, P0_4, P1_4, P50_4, P51_4);
    REDUCE6(v5, F5, P0_5, P1_5, P50_5, P51_5);

    if (l < KKN) {
        const int i = l / 3, j = l % 3;   // row-window i, col-window j
        // select row-window arrays via ternaries (keeps everything in VGPRs)
        const float Fs   = (i == 0) ? F0    : (i == 1) ? F1    : F2;
        const float A0s  = (i == 0) ? P0_0  : (i == 1) ? P0_1  : P0_2;
        const float A1s  = (i == 0) ? P1_0  : (i == 1) ? P1_1  : P1_2;
        const float C0s  = (i == 0) ? P50_0 : (i == 1) ? P50_1 : P50_2;
        const float C1s  = (i == 0) ? P51_0 : (i == 1) ? P51_1 : P51_2;
        const float Fq   = (i == 0) ? F3    : (i == 1) ? F4    : F5;
        const float A0q  = (i == 0) ? P0_3  : (i == 1) ? P0_4  : P0_5;
        const float A1q  = (i == 0) ? P1_3  : (i == 1) ? P1_4  : P1_5;
        const float C0q  = (i == 0) ? P50_3 : (i == 1) ? P50_4 : P50_5;
        const float C1q  = (i == 0) ? P51_3 : (i == 1) ? P51_4 : P51_5;
        // col-window j=0: cols 0..49 (drop 50,51); j=1: 1..50; j=2: 2..51
        const float corrS = (j == 0) ? (C0s + C1s) : (j == 1) ? (A0s + C1s) : (A0s + A1s);
        const float corrQ = (j == 0) ? (C0q + C1q) : (j == 1) ? (A0q + C1q) : (A0q + A1q);
        sT[w][l] = Fs - corrS;
        sQ[w][l] = Fq - corrQ;
    }
    __syncthreads();

    // ---- Phase 2: contraction over kk, then over c ----
    if (t < CC * OO) {                    // t = c*16 + o
        const int c = t >> 4, o = t & 15;
        const float* wp = sW + (o * CC + c) * KKN;
        float size = 0.f, s1 = 0.f, sq = 0.f;
        #pragma unroll
        for (int k = 0; k < KKN; ++k) {
            const float wv = wp[k];
            size += wv;
            s1   += wv * sT[c][k];
            sq   += wv * wv * sQ[c][k];
        }
        partial[t] = (sq - s1 * s1 * INV_L2) / size;
    }
    __syncthreads();
    if (t < OO) {                         // t = o
        float a = 0.f;
        #pragma unroll
        for (int c = 0; c < CC; ++c) a += partial[c * 16 + t];
        accO[t] = a;
    }
    __syncthreads();
    if (t < OO * OO) {                    // t = i*16 + o
        const int i = t >> 4, o = t & 15;
        out[i * (NN * OO) + n * OO + o] = accO[o] + sB[i * CC + n];
    }
}

extern "C" void kernel_launch(void* const* d_in, const int* in_sizes, int n_in,
                              void* d_out, int out_size, void* d_ws, size_t ws_size,
                              hipStream_t stream) {
    const float* x  = (const float*)d_in[0];
    const float* Wt = (const float*)d_in[1];
    const float* B  = (const float*)d_in[2];
    float* out = (float*)d_out;

    tvar_onepass<<<NN, 1024, 0, stream>>>(x, Wt, B, out);
}